// Round 12
// baseline (255.592 us; speedup 1.0000x reference)
//
#include <hip/hip_runtime.h>
#include <math.h>

// Problem constants (match reference setup_inputs)
constexpr int B = 128, T = 128, F = 2048, KW = 5;
#define ALPHA 0.9f
#define BETA  0.1f
#define DECAY 0.9f
#define GAMMA 0.5f

// native clang vector type
typedef float v2f __attribute__((ext_vector_type(2)));

// Full-range atan, max err ~2e-6 rad (validated R6/R7: absmax unchanged).
__device__ __forceinline__ float atan_fast(float z) {
    float az  = __builtin_fabsf(z);
    float inv = __builtin_amdgcn_rcpf(az);
    bool  big = az > 1.0f;
    float u   = big ? inv : az;
    float u2  = u * u;
    float p   = fmaf(u2, -0.01172120f, 0.05265332f);
    p = fmaf(u2, p, -0.11643287f);
    p = fmaf(u2, p,  0.19354346f);
    p = fmaf(u2, p, -0.33262347f);
    p = fmaf(u2, p,  0.99997726f);
    float r = u * p;
    r = big ? (1.57079632679f - r) : r;
    return copysignf(r, z);
}

// R11 A/B: identical to the R9 kernel (91us, XCD remap + fast-atan) except
// the output stores are PLAIN (cached) instead of nontemporal. The NT hint
// is the single invariant shared by all six 91-103us variants and was never
// isolated. Readings: dur drop -> NT writes were throttling the controller;
// FETCH_SIZE jump (+~128MB) -> NT was protecting x's L3 residency (restore
// it); no change -> both exonerated, fabric ceiling stands.
__global__ __launch_bounds__(256) void lif_fused_kernel(
    const float* __restrict__ x,        // [B,T,F]
    const float* __restrict__ thr0p,    // scalar
    const float* __restrict__ convw,    // [1,1,KW]
    const float* __restrict__ convb,    // [1]
    const float* __restrict__ sattn,    // [1]
    float* __restrict__ out)            // [B*T*F] spikes ++ [B*F] mem
{
    // ---- XCD-locality block remap (bijective on 0..511) ----
    const int raw    = blockIdx.x;       // 512 blocks
    const int xcd    = raw & 7;          // presumed XCD id (round-robin)
    const int slot   = raw >> 3;         // 0..63 within XCD
    const int b      = xcd * 16 + (slot >> 2);   // 16 b-rows per XCD
    const int fchunk = slot & 3;                 // 4 f-chunks of this b-row
    const int f      = fchunk * 512 + (int)threadIdx.x * 2;

    const float w0 = convw[0], w1 = convw[1], w2 = convw[2],
                w3 = convw[3], w4 = convw[4];
    const float cb   = convb[0];
    const float thr0 = thr0p[0];
    const float sa   = sattn[0];

    const float* xp = x + (size_t)b * T * F + f;

    // ---- pass 1: sum of x over t (8 partial sums, 8 loads in flight) ----
    v2f s0 = {0.f,0.f}, s1 = {0.f,0.f}, s2 = {0.f,0.f}, s3 = {0.f,0.f},
        s4 = {0.f,0.f}, s5 = {0.f,0.f}, s6 = {0.f,0.f}, s7 = {0.f,0.f};
#pragma unroll 2
    for (int t = 0; t < T; t += 8) {
        v2f v0 = *(const v2f*)(xp + (size_t)(t + 0) * F);
        v2f v1 = *(const v2f*)(xp + (size_t)(t + 1) * F);
        v2f v2 = *(const v2f*)(xp + (size_t)(t + 2) * F);
        v2f v3 = *(const v2f*)(xp + (size_t)(t + 3) * F);
        v2f v4 = *(const v2f*)(xp + (size_t)(t + 4) * F);
        v2f v5 = *(const v2f*)(xp + (size_t)(t + 5) * F);
        v2f v6 = *(const v2f*)(xp + (size_t)(t + 6) * F);
        v2f v7 = *(const v2f*)(xp + (size_t)(t + 7) * F);
        s0 += v0; s1 += v1; s2 += v2; s3 += v3;
        s4 += v4; s5 += v5; s6 += v6; s7 += v7;
    }
    v2f sx = ((s0 + s1) + (s2 + s3)) + ((s4 + s5) + (s6 + s7));

    // edge values (L2/L3-warm re-reads)
    v2f e0  = *(const v2f*)(xp);                      // x[0]
    v2f e1  = *(const v2f*)(xp + (size_t)F);          // x[1]
    v2f em2 = *(const v2f*)(xp + (size_t)(T - 2) * F);// x[T-2]
    v2f em1 = *(const v2f*)(xp + (size_t)(T - 1) * F);// x[T-1]

    // sum_t conv[t] = W*sum_t x - (w3+w4)x[0] - w4 x[1] - w0 x[T-2] - (w0+w1)x[T-1] + T*cb
    const float W = ((w0 + w1) + (w2 + w3)) + w4;
    v2f csum;
    csum.x = fmaf(W, sx.x, (float)T * cb)
           - (w3 + w4) * e0.x - w4 * e1.x - w0 * em2.x - (w0 + w1) * em1.x;
    csum.y = fmaf(W, sx.y, (float)T * cb)
           - (w3 + w4) * e0.y - w4 * e1.y - w0 * em2.y - (w0 + w1) * em1.y;

    // ---- spatial attention gate ----
    v2f scale;
    {
        float zx = sa * (csum.x * (1.0f / (float)T));
        float zy = sa * (csum.y * (1.0f / (float)T));
        scale.x = 1.0f + GAMMA * (1.0f / (1.0f + expf(-zx)));
        scale.y = 1.0f + GAMMA * (1.0f / (1.0f + expf(-zy)));
    }

    // ---- pass 2: rolling conv + LIF recurrence ----
    const float PIH    = 1.57079632679f;        // pi/2
    const float INV2PI = 0.15915494309f;        // 1/(2*pi)
    const float thc    = (1.0f - ALPHA) * thr0;

    v2f mem = {0.f, 0.f};
    v2f thr = {thr0, thr0};
    v2f h1 = {0.f, 0.f}, h2 = {0.f, 0.f};
    // window regs: a=x[t-2], bb=x[t-1], c=x[t], d=x[t+1]
    v2f a = {0.f, 0.f}, bb = {0.f, 0.f}, c = e0, d = e1;

    float* sp = out + (size_t)b * T * F + f;                  // spikes [B,T,F]
    float* mp = out + (size_t)B * T * F + (size_t)b * F + f;  // mem [B,F]

    auto lif_step = [&](int t, v2f e) {
        float cx = fmaf(w0, a.x, fmaf(w1, bb.x, fmaf(w2, c.x,
                   fmaf(w3, d.x, fmaf(w4, e.x, cb)))));
        float cy = fmaf(w0, a.y, fmaf(w1, bb.y, fmaf(w2, c.y,
                   fmaf(w3, d.y, fmaf(w4, e.y, cb)))));
        mem.x = fmaf(DECAY, mem.x, cx * scale.x);
        mem.y = fmaf(DECAY, mem.y, cy * scale.y);
        float spx = fmaf(atan_fast(PIH * (mem.x - thr.x)), INV2PI, 0.25f);
        float spy = fmaf(atan_fast(PIH * (mem.y - thr.y)), INV2PI, 0.25f);
        float avx = (h1.x + h2.x + spx) * (1.0f / 3.0f);
        float avy = (h1.y + h2.y + spy) * (1.0f / 3.0f);
        h1 = h2; h2.x = spx; h2.y = spy;
        thr.x = fmaf(ALPHA, thr.x, fmaf(BETA, avx, thc));
        thr.y = fmaf(ALPHA, thr.y, fmaf(BETA, avy, thc));
        mem.x = fmaf(-spx, thr.x, mem.x);
        mem.y = fmaf(-spy, thr.y, mem.y);
        v2f spv = {spx, spy};
        *(v2f*)(sp + (size_t)t * F) = spv;      // PLAIN store (A/B vs NT)
        a = bb; bb = c; c = d; d = e;
    };

#pragma unroll 8
    for (int t = 0; t < T - 2; ++t) {
        v2f e = *(const v2f*)(xp + (size_t)(t + 2) * F);
        lif_step(t, e);
    }
    lif_step(T - 2, (v2f){0.f, 0.f});   // e = 0 (zero pad)
    lif_step(T - 1, (v2f){0.f, 0.f});   // d = e = 0

    *(v2f*)mp = mem;                    // PLAIN store (A/B vs NT)
}

extern "C" void kernel_launch(void* const* d_in, const int* in_sizes, int n_in,
                              void* d_out, int out_size, void* d_ws, size_t ws_size,
                              hipStream_t stream) {
    const float* x     = (const float*)d_in[0];
    const float* thr0  = (const float*)d_in[1];
    const float* convw = (const float*)d_in[2];
    const float* convb = (const float*)d_in[3];
    const float* sattn = (const float*)d_in[4];
    float* out = (float*)d_out;

    const int total = B * F / 2;        // one thread per 2 (b,f) series
    const int block = 256;
    const int grid  = total / block;    // 512 blocks

    lif_fused_kernel<<<grid, block, 0, stream>>>(x, thr0, convw, convb, sattn, out);
}

// Round 17
// 252.588 us; speedup vs baseline: 1.0119x; 1.0119x over previous
//
#include <hip/hip_runtime.h>
#include <math.h>

// Problem constants (match reference setup_inputs)
constexpr int B = 128, T = 128, F = 2048, KW = 5;
#define ALPHA 0.9f
#define BETA  0.1f
#define DECAY 0.9f
#define GAMMA 0.5f

// native clang vector type
typedef float v2f __attribute__((ext_vector_type(2)));

// Full-range atan, max err ~2e-6 rad (validated R6/R7: absmax unchanged).
__device__ __forceinline__ float atan_fast(float z) {
    float az  = __builtin_fabsf(z);
    float inv = __builtin_amdgcn_rcpf(az);
    bool  big = az > 1.0f;
    float u   = big ? inv : az;
    float u2  = u * u;
    float p   = fmaf(u2, -0.01172120f, 0.05265332f);
    p = fmaf(u2, p, -0.11643287f);
    p = fmaf(u2, p,  0.19354346f);
    p = fmaf(u2, p, -0.33262347f);
    p = fmaf(u2, p,  0.99997726f);
    float r = u * p;
    r = big ? (1.57079632679f - r) : r;
    return copysignf(r, z);
}

// R12 experiment: split-phase. All prior single-kernel variants ran three
// concurrent TCC streams (HBM read + L3 re-read + write) from blocks in
// unsynchronized phases, plateauing at ~4.3 TB/s combined. Split:
//   k1 = pure streaming HBM read -> scale[B,F] (1MB to d_ws)
//   k2 = L3-served re-read + write stream (x stays L3-resident: k1 writes 1MB)
// Each kernel's roofline is a known quantity; k1 doubles as a diagnostic
// (if the simplest pure-read kernel also pins at 2.9 TB/s, the cap is
// pattern-independent and 91us was the floor).

__global__ __launch_bounds__(256) void scale_kernel(
    const float* __restrict__ x,        // [B,T,F]
    const float* __restrict__ thr0p,
    const float* __restrict__ convw,    // [1,1,KW]
    const float* __restrict__ convb,    // [1]
    const float* __restrict__ sattn,    // [1]
    float* __restrict__ scalebuf)       // [B,F] (workspace)
{
    const int tid   = blockIdx.x * blockDim.x + threadIdx.x;
    const int fpair = tid & (F / 2 - 1);
    const int b     = tid >> 10;
    const int f     = fpair * 2;

    const float w0 = convw[0], w1 = convw[1], w2 = convw[2],
                w3 = convw[3], w4 = convw[4];
    const float cb = convb[0];
    const float sa = sattn[0];

    const float* xp = x + (size_t)b * T * F + f;

    // streaming sum over t (8 partial sums, 8 loads in flight)
    v2f s0 = {0.f,0.f}, s1 = {0.f,0.f}, s2 = {0.f,0.f}, s3 = {0.f,0.f},
        s4 = {0.f,0.f}, s5 = {0.f,0.f}, s6 = {0.f,0.f}, s7 = {0.f,0.f};
#pragma unroll 2
    for (int t = 0; t < T; t += 8) {
        v2f v0 = *(const v2f*)(xp + (size_t)(t + 0) * F);
        v2f v1 = *(const v2f*)(xp + (size_t)(t + 1) * F);
        v2f v2 = *(const v2f*)(xp + (size_t)(t + 2) * F);
        v2f v3 = *(const v2f*)(xp + (size_t)(t + 3) * F);
        v2f v4 = *(const v2f*)(xp + (size_t)(t + 4) * F);
        v2f v5 = *(const v2f*)(xp + (size_t)(t + 5) * F);
        v2f v6 = *(const v2f*)(xp + (size_t)(t + 6) * F);
        v2f v7 = *(const v2f*)(xp + (size_t)(t + 7) * F);
        s0 += v0; s1 += v1; s2 += v2; s3 += v3;
        s4 += v4; s5 += v5; s6 += v6; s7 += v7;
    }
    v2f sx = ((s0 + s1) + (s2 + s3)) + ((s4 + s5) + (s6 + s7));

    v2f e0  = *(const v2f*)(xp);
    v2f e1  = *(const v2f*)(xp + (size_t)F);
    v2f em2 = *(const v2f*)(xp + (size_t)(T - 2) * F);
    v2f em1 = *(const v2f*)(xp + (size_t)(T - 1) * F);

    // sum_t conv[t] = W*sum_t x - (w3+w4)x[0] - w4 x[1] - w0 x[T-2] - (w0+w1)x[T-1] + T*cb
    const float W = ((w0 + w1) + (w2 + w3)) + w4;
    v2f csum;
    csum.x = fmaf(W, sx.x, (float)T * cb)
           - (w3 + w4) * e0.x - w4 * e1.x - w0 * em2.x - (w0 + w1) * em1.x;
    csum.y = fmaf(W, sx.y, (float)T * cb)
           - (w3 + w4) * e0.y - w4 * e1.y - w0 * em2.y - (w0 + w1) * em1.y;

    v2f scale;
    scale.x = 1.0f + GAMMA * (1.0f / (1.0f + expf(-sa * (csum.x * (1.0f/(float)T)))));
    scale.y = 1.0f + GAMMA * (1.0f / (1.0f + expf(-sa * (csum.y * (1.0f/(float)T)))));

    *(v2f*)(scalebuf + (size_t)b * F + f) = scale;
}

__global__ __launch_bounds__(256) void lif_kernel(
    const float* __restrict__ x,        // [B,T,F]
    const float* __restrict__ thr0p,
    const float* __restrict__ convw,
    const float* __restrict__ convb,
    const float* __restrict__ sattn,
    const float* __restrict__ scalebuf, // [B,F]
    float* __restrict__ out)            // [B*T*F] spikes ++ [B*F] mem
{
    const int tid   = blockIdx.x * blockDim.x + threadIdx.x;
    const int fpair = tid & (F / 2 - 1);
    const int b     = tid >> 10;
    const int f     = fpair * 2;

    const float w0 = convw[0], w1 = convw[1], w2 = convw[2],
                w3 = convw[3], w4 = convw[4];
    const float cb   = convb[0];
    const float thr0 = thr0p[0];

    const float* xp = x + (size_t)b * T * F + f;
    const v2f scale = *(const v2f*)(scalebuf + (size_t)b * F + f);

    const float PIH    = 1.57079632679f;
    const float INV2PI = 0.15915494309f;
    const float thc    = (1.0f - ALPHA) * thr0;

    v2f mem = {0.f, 0.f};
    v2f thr = {thr0, thr0};
    v2f h1 = {0.f, 0.f}, h2 = {0.f, 0.f};
    v2f e0 = *(const v2f*)(xp);
    v2f e1 = *(const v2f*)(xp + (size_t)F);
    // window regs: a=x[t-2], bb=x[t-1], c=x[t], d=x[t+1]
    v2f a = {0.f, 0.f}, bb = {0.f, 0.f}, c = e0, d = e1;

    float* sp = out + (size_t)b * T * F + f;
    float* mp = out + (size_t)B * T * F + (size_t)b * F + f;

    auto lif_step = [&](int t, v2f e) {
        float cx = fmaf(w0, a.x, fmaf(w1, bb.x, fmaf(w2, c.x,
                   fmaf(w3, d.x, fmaf(w4, e.x, cb)))));
        float cy = fmaf(w0, a.y, fmaf(w1, bb.y, fmaf(w2, c.y,
                   fmaf(w3, d.y, fmaf(w4, e.y, cb)))));
        mem.x = fmaf(DECAY, mem.x, cx * scale.x);
        mem.y = fmaf(DECAY, mem.y, cy * scale.y);
        float spx = fmaf(atan_fast(PIH * (mem.x - thr.x)), INV2PI, 0.25f);
        float spy = fmaf(atan_fast(PIH * (mem.y - thr.y)), INV2PI, 0.25f);
        float avx = (h1.x + h2.x + spx) * (1.0f / 3.0f);
        float avy = (h1.y + h2.y + spy) * (1.0f / 3.0f);
        h1 = h2; h2.x = spx; h2.y = spy;
        thr.x = fmaf(ALPHA, thr.x, fmaf(BETA, avx, thc));
        thr.y = fmaf(ALPHA, thr.y, fmaf(BETA, avy, thc));
        mem.x = fmaf(-spx, thr.x, mem.x);
        mem.y = fmaf(-spy, thr.y, mem.y);
        v2f spv = {spx, spy};
        __builtin_nontemporal_store(spv, (v2f*)(sp + (size_t)t * F));
        a = bb; bb = c; c = d; d = e;
    };

#pragma unroll 8
    for (int t = 0; t < T - 2; ++t) {
        v2f e = *(const v2f*)(xp + (size_t)(t + 2) * F);   // L3-hit
        lif_step(t, e);
    }
    lif_step(T - 2, (v2f){0.f, 0.f});
    lif_step(T - 1, (v2f){0.f, 0.f});

    __builtin_nontemporal_store(mem, (v2f*)mp);
}

extern "C" void kernel_launch(void* const* d_in, const int* in_sizes, int n_in,
                              void* d_out, int out_size, void* d_ws, size_t ws_size,
                              hipStream_t stream) {
    const float* x     = (const float*)d_in[0];
    const float* thr0  = (const float*)d_in[1];
    const float* convw = (const float*)d_in[2];
    const float* convb = (const float*)d_in[3];
    const float* sattn = (const float*)d_in[4];
    float* out      = (float*)d_out;
    float* scalebuf = (float*)d_ws;     // B*F*4 = 1 MiB

    const int total = B * F / 2;        // one thread per 2 (b,f) series
    const int block = 256;
    const int grid  = total / block;    // 512 blocks

    scale_kernel<<<grid, block, 0, stream>>>(x, thr0, convw, convb, sattn, scalebuf);
    lif_kernel<<<grid, block, 0, stream>>>(x, thr0, convw, convb, sattn, scalebuf, out);
}